// Round 17
// baseline (7893.610 us; speedup 1.0000x reference)
//
#include <hip/hip_runtime.h>

// SNN-MNIST forward + STDP, MI355X persistent cooperative kernel.
// Round 21: MEASUREMENT ROUND (barrier amplification). r20 source,
// byte-identical semantics, except both in-loop grid barriers are DOUBLED
// (4/step instead of 2, +400 total). A back-to-back duplicate gbar has no
// outstanding stores (drain free, no skew), so the dur delta vs r20 (6310)
// = 2x pure release cost (flag store -> cross-L3 visibility -> poll).
// Decision tree (delta us/step): >=4 -> rebuild release; 1.5-4 -> attack
// drain side; <=1 -> barriers exonerated, measure phase 1 next.

#define T_STEPS 200
#define BATCH   256
#define INQ     784
#define NOUT    400
#define NP      512
#define GRID    256
#define NTHR    512
#define NBN     7              // n-blocks of 64 cols
#define ABLK    175            // 25 i-blocks x 7 n-blocks

// ws layout (float offsets)
#define OFF_WT    0            // Wt [785][512] (row 784 = zero pad for gather)
#define OFF_SYN   401920       // syn [256][512]         (block-private)
#define OFF_MEM   532992       // mem [256][512]         (block-private)
#define OFF_SPPO  664064       // interleaved (spk,post): [256][1024]  (sc1)
#define OFF_TRM   926208       // merged (tr,img): [256][1568]        (sc1)
#define OFF_WIN   1327616      // int win[256]           (block-private)
#define OFF_ANY   1327872      // u32 anyspk[2][256]     (sc1, ping-pong)
#define OFF_BARF  1328384      // u32 barf[256]: all-to-all barrier flags
#define WS_FLOATS 1332224

// ---- agent-coherent (sc1) access helpers ----
__device__ __forceinline__ float ld_coh(const float* p) {
  return __hip_atomic_load(p, __ATOMIC_RELAXED, __HIP_MEMORY_SCOPE_AGENT);
}
__device__ __forceinline__ float2 ld_coh2(const float* p) {
  union { unsigned long long u; float2 f; } c;
  c.u = __hip_atomic_load((const unsigned long long*)p, __ATOMIC_RELAXED,
                          __HIP_MEMORY_SCOPE_AGENT);
  return c.f;
}
__device__ __forceinline__ void st_coh(float* p, float v) {
  __hip_atomic_store(p, v, __ATOMIC_RELAXED, __HIP_MEMORY_SCOPE_AGENT);
}
__device__ __forceinline__ void st_coh2(float* p, float2 v) {
  union { unsigned long long u; float2 f; } c; c.f = v;
  __hip_atomic_store((unsigned long long*)p, c.u, __ATOMIC_RELAXED,
                     __HIP_MEMORY_SCOPE_AGENT);
}
__device__ __forceinline__ void st_cohu(unsigned* p, unsigned v) {
  __hip_atomic_store(p, v, __ATOMIC_RELAXED, __HIP_MEMORY_SCOPE_AGENT);
}
__device__ __forceinline__ unsigned long long ld_cohu64(const unsigned long long* p) {
  return __hip_atomic_load(p, __ATOMIC_RELAXED, __HIP_MEMORY_SCOPE_AGENT);
}

__device__ __forceinline__ void gl_lds16c(const float* g, float* l) {      // sc1
  __builtin_amdgcn_global_load_lds(
      (const __attribute__((address_space(1))) void*)g,
      (__attribute__((address_space(3))) void*)l, 16, 0, 0x10);
}

// All-to-all flag barrier, k = 1-based ordinal.
__device__ __forceinline__ void gbar(unsigned* barf, unsigned k, int blk) {
  __syncthreads();
  if (threadIdx.x == 0)
    st_cohu(barf + blk, k);
  if (threadIdx.x < 64) {
    const unsigned long long* p =
        (const unsigned long long*)barf + (threadIdx.x << 1);
    for (;;) {
      unsigned long long a = ld_cohu64(p);
      unsigned long long bq = ld_cohu64(p + 1);
      unsigned m0 = (unsigned)a, m1 = (unsigned)(a >> 32);
      unsigned m2 = (unsigned)bq, m3 = (unsigned)(bq >> 32);
      unsigned mn = m0 < m1 ? m0 : m1;
      unsigned mo = m2 < m3 ? m2 : m3;
      mn = mn < mo ? mn : mo;
      if (__all(mn >= k)) break;
      __builtin_amdgcn_s_sleep(1);
    }
  }
  __syncthreads();
}

__global__ void __launch_bounds__(NTHR, 2) snn_kernel(
    const float* __restrict__ img,   // [200][256][784]
    const float* __restrict__ Win,   // [400][784]
    float* __restrict__ out,         // mem_rec | spk_rec | W_final
    float* ws)
{
  float* Wt    = ws + OFF_WT;
  float* syn   = ws + OFF_SYN;
  float* mem   = ws + OFF_MEM;
  float* sppo  = ws + OFF_SPPO;
  float* trm   = ws + OFF_TRM;
  int*   win   = (int*)(ws + OFF_WIN);
  unsigned* anyspk = (unsigned*)(ws + OFF_ANY);
  unsigned* barf   = (unsigned*)(ws + OFF_BARF);

  float* mem_rec = out;
  float* spk_rec = out + (size_t)T_STEPS * BATCH * NOUT;
  float* Wout    = out + (size_t)2 * T_STEPS * BATCH * NOUT;

  const int tid = threadIdx.x;
  const int blk = blockIdx.x;
  unsigned bt = 0;                    // barrier ordinal

  __shared__ float stg_ti[16384];     // merged (tr,img) [256][64], persistent
  __shared__ float stg_sp[2][8192];   // sppo chunk dbuf [64][128]
  __shared__ float s_trrow[INQ];      // block-own pre-trace row
  __shared__ int s_list[2][832];      // double-buffered active lists
  __shared__ int s_cnt2[2];
  __shared__ int s_any;
  __shared__ int s_red[8];

  // phase-2 geometry: 25 i-blocks (32 rows) x 7 n-blocks (64 cols)
  const int bi = blk / NBN, bn = blk % NBN;
  const int ib0 = bi * 32, nb0 = bn * 64;
  const int scol = 2 * nb0 + (tid & 31) * 4;        // sppo col
  int colf = 2 * ib0 + (tid & 15) * 4;
  if (colf > 2 * INQ - 4) colf = 2 * INQ - 4;

  // per-thread phase-2 tile: 2 i-rows x 2 n-cols
  const int ib = ib0 + (tid >> 5) * 2;
  const int nb = nb0 + (tid & 31) * 2;
  const int tioff = (tid >> 5) * 4;
  const int soff  = (tid & 31) * 4;

  // ---- init: Wt[i][n] = Win[n][i]; merged row {tr=0, img_0} ----
  for (int e = blk * NTHR + tid; e < NOUT * INQ; e += GRID * NTHR) {
    int n = e / INQ, i = e % INQ;
    st_coh(Wt + (size_t)i * NP + n, Win[e]);
  }
  for (int i = tid; i < INQ; i += NTHR)
    st_coh2(trm + (size_t)blk * (2 * INQ) + 2 * i,
            make_float2(0.0f, img[(size_t)blk * INQ + i]));
  for (int i = tid; i < INQ; i += NTHR) s_trrow[i] = 0.0f;
  // init compaction of img[0] into s_list[0] (wave 0)
  if (tid < 64) {
    const float* im0 = img + (size_t)blk * INQ;
    int base = 0;
    for (int c = 0; c < INQ; c += 64) {
      int i = c + tid;
      bool act = (i < INQ) && (im0[i] != 0.0f);
      unsigned long long m = __ballot(act);
      if (act)
        s_list[0][base + (int)__popcll(m & ((1ull << tid) - 1ull))] = i;
      base += (int)__popcll(m);
    }
    if (tid == 0) {
      int cr = (base + 63) & ~63;
      for (int j = base; j < cr; ++j) s_list[0][j] = 784;
      s_cnt2[0] = cr;
    }
  }
  ++bt; gbar(barf, bt, blk);

  // step-0 ti prefetch (8 passes x 32 rows; lane-contiguous LDS dest)
  if (blk < ABLK) {
    #pragma unroll
    for (int q = 0; q < 8; ++q) {
      int br = q * 32 + (tid >> 4);
      gl_lds16c(trm + (size_t)br * (2 * INQ) + colf,
                &stg_ti[br * 64 + (tid & 15) * 4]);
    }
  }

  for (int t = 0; t < T_STEPS; ++t) {
    const int tn = (t + 1 < T_STEPS) ? t + 1 : t;

    // ================= phase 1: block b = batch row =================
    {
      const int b = blk;
      const float* imrow = img + ((size_t)t * BATCH + b) * INQ;
      const float* imnext = img + ((size_t)tn * BATCH + b) * INQ;
      float* trmrow = trm + (size_t)b * (2 * INQ);
      if (tid < 448) {
        // tids 0-447: trace recurrence from block-own LDS row; write merged
        // {tr_{t+1}, img_{t+1}} pair for next step's phase 2
        for (int i = tid; i < INQ; i += 448) {
          float trv = fmaf(0.9f, s_trrow[i], imrow[i]);
          s_trrow[i] = trv;
          st_coh2(trmrow + 2 * i, make_float2(trv, imnext[i]));
        }
      } else {
        // wave 7: anyspk gather + compaction of img[t+1] into buf[(t+1)&1]
        const int l = tid - 448;
        unsigned long long ax = 0ull, ay = 0ull;
        if (t > 0) {
          const unsigned long long* ap =
              (const unsigned long long*)(anyspk + ((t - 1) & 1) * 256) +
              (l << 1);
          ax = ld_cohu64(ap);
          ay = ld_cohu64(ap + 1);
        }
        int* lst = s_list[(t + 1) & 1];
        int base = 0;
        for (int c = 0; c < INQ; c += 64) {
          int i = c + l;
          bool act = (i < INQ) && (imnext[i] != 0.0f);
          unsigned long long m = __ballot(act);
          if (act) lst[base + (int)__popcll(m & ((1ull << l) - 1ull))] = i;
          base += (int)__popcll(m);
        }
        int anyv = __any((ax | ay) != 0ull);
        if (l == 0) {
          int cr = (base + 63) & ~63;
          for (int j = base; j < cr; ++j) lst[j] = 784;  // zero pad row
          s_cnt2[(t + 1) & 1] = cr;
          s_any = anyv;
        }
      }
      __syncthreads();
      const int cnt = s_cnt2[t & 1];    // multiple of 64 (precomputed)
      const int* lst = s_list[t & 1];
      const int anyPrev = (t > 0) ? s_any : 0;
      const int wPrev = win[b];
      int localmin = 0x7fffffff;

      if (tid < NOUT) {
        const int n0 = tid;             // one neuron per thread
        const size_t sidx = (size_t)b * NP + n0;
        float* sprow = sppo + (size_t)b * 2 * NP + 2 * n0;
        float2 sp2 = ld_coh2(sprow);    // (spk, post)
        float sv = syn[sidx];
        if (anyPrev && n0 != wPrev) sv -= 0.1f;
        float c0 = 0.f;
        for (int j = 0; j < cnt; j += 64) {  // 64 coherent loads in flight
          float wv[64];
          #pragma unroll
          for (int u = 0; u < 64; ++u)
            wv[u] = ld_coh(Wt + (size_t)lst[j + u] * NP + n0);
          #pragma unroll
          for (int u = 0; u < 64; ++u) c0 += wv[u];
        }
        float mv = mem[sidx];
        float syn0 = fmaf(0.9f, sv, c0);
        float r0 = (mv > 1.0f) ? 1.0f : 0.0f;
        float m0 = fmaf(0.8f, mv, syn0) - r0;
        float s0 = (m0 > 1.0f) ? 1.0f : 0.0f;
        syn[sidx] = syn0;
        mem[sidx] = m0;
        float p0 = fmaf(0.9f, sp2.y, s0);
        st_coh2(sprow, make_float2(s0, p0));
        const size_t ridx = (size_t)t * BATCH * NOUT + (size_t)b * NOUT + n0;
        mem_rec[ridx] = m0;
        spk_rec[ridx] = s0;
        if (s0 != 0.f) localmin = n0;
      }
      // ballot winner reduction
      unsigned long long mm = __ballot(localmin != 0x7fffffff);
      int wmin = 0x7fffffff;
      if (mm) {
        int src = __ffsll(mm) - 1;
        wmin = __shfl(localmin, src);
      }
      if ((tid & 63) == 0) s_red[tid >> 6] = wmin;
      __syncthreads();
      if (tid == 0) {
        int w4 = min(min(min(s_red[0], s_red[1]), min(s_red[2], s_red[3])),
                     min(min(s_red[4], s_red[5]), min(s_red[6], s_red[7])));
        win[b] = (w4 == 0x7fffffff) ? 0 : w4;
        st_cohu(anyspk + (t & 1) * 256 + blk,
                (w4 != 0x7fffffff) ? 1u : 0u);
      }
    }
    ++bt; gbar(barf, bt, blk);
    ++bt; gbar(barf, bt, blk);          // MEASUREMENT: duplicate barrier

    // ================= phase 2: STDP weight update =================
    // ti resident in LDS; 4 merged chunks of 64 b-rows, 2-deep sppo dbuf.
    if (blk < ABLK) {
      const bool active = (ib < INQ) && (nb < NOUT);

      float2 wl0, wl1;
      if (active) {
        wl0 = ld_coh2(Wt + (size_t)(ib + 0) * NP + nb);
        wl1 = ld_coh2(Wt + (size_t)(ib + 1) * NP + nb);
      }

      float a00 = 0, a01 = 0, a10 = 0, a11 = 0;

      #define SPSTG(c_, buf_) {                                                \
        for (int q = 0; q < 4; ++q) {                                          \
          int br = (c_) * 64 + q * 16 + (tid >> 5);                            \
          gl_lds16c(sppo + (size_t)br * 1024 + scol,                           \
                    &stg_sp[buf_][(q * 16 + (tid >> 5)) * 128 +                \
                                  (tid & 31) * 4]);                            \
        }                                                                      \
      }

      SPSTG(0, 0); SPSTG(1, 1);
      for (int c = 0; c < 4; ++c) {
        if (c == 0) __builtin_amdgcn_s_waitcnt(0x0F74);  // vmcnt(4)
        else        __builtin_amdgcn_s_waitcnt(0x0F70);  // vmcnt(0)
        __builtin_amdgcn_sched_barrier(0);
        __builtin_amdgcn_s_barrier();
        if (c >= 1 && c <= 2) SPSTG(c + 1, (c + 1) & 1);
        if (active) {
          const float* Lti = &stg_ti[(c * 64) * 64 + tioff];
          const float* Lsp = &stg_sp[c & 1][soff];
          #pragma unroll 8
          for (int bb = 0; bb < 64; ++bb) {       // b ascending: exact order
            float4 q4 = *(const float4*)(Lti + bb * 64);   // tr0,im0,tr1,im1
            float4 sp = *(const float4*)(Lsp + bb * 128);  // s0,p0,s1,p1
            a00 = fmaf(q4.x, sp.x, fmaf(q4.y, -sp.y, a00));
            a01 = fmaf(q4.x, sp.z, fmaf(q4.y, -sp.w, a01));
            a10 = fmaf(q4.z, sp.x, fmaf(q4.w, -sp.y, a10));
            a11 = fmaf(q4.z, sp.z, fmaf(q4.w, -sp.w, a11));
          }
        }
      }
      #undef SPSTG

      // RACE FIX: all waves finish chunk-3 LDS reads before the prefetch
      // overwrites stg_ti.
      __builtin_amdgcn_s_barrier();

      // next-step ti prefetch streams in the epilogue + barrier shadow
      if (t + 1 < T_STEPS) {
        #pragma unroll
        for (int q = 0; q < 8; ++q) {
          int br = q * 32 + (tid >> 4);
          gl_lds16c(trm + (size_t)br * (2 * INQ) + colf,
                    &stg_ti[br * 64 + (tid & 15) * 4]);
        }
      }
      if (active) {
        float2 wv;
        wv = wl0;
        wv.x = fminf(fmaxf(wv.x + 1e-3f * a00, 0.f), 1.f);
        wv.y = fminf(fmaxf(wv.y + 1e-3f * a01, 0.f), 1.f);
        st_coh2(Wt + (size_t)(ib + 0) * NP + nb, wv);
        wv = wl1;
        wv.x = fminf(fmaxf(wv.x + 1e-3f * a10, 0.f), 1.f);
        wv.y = fminf(fmaxf(wv.y + 1e-3f * a11, 0.f), 1.f);
        st_coh2(Wt + (size_t)(ib + 1) * NP + nb, wv);
      }
    }
    ++bt; gbar(barf, bt, blk);
    ++bt; gbar(barf, bt, blk);          // MEASUREMENT: duplicate barrier
  }

  // ---- final: W_out[n][i] = Wt[i][n] ----
  for (int e = blk * NTHR + tid; e < NOUT * INQ; e += GRID * NTHR) {
    int n = e / INQ, i = e % INQ;
    Wout[e] = ld_coh(Wt + (size_t)i * NP + n);
  }
}

extern "C" void kernel_launch(void* const* d_in, const int* in_sizes, int n_in,
                              void* d_out, int out_size, void* d_ws, size_t ws_size,
                              hipStream_t stream) {
  const float* img = (const float*)d_in[0];
  const float* W   = (const float*)d_in[1];
  float* out = (float*)d_out;
  float* ws  = (float*)d_ws;

  hipMemsetAsync(d_ws, 0, (size_t)WS_FLOATS * sizeof(float), stream);

  void* args[] = { (void*)&img, (void*)&W, (void*)&out, (void*)&ws };
  hipError_t rc = hipLaunchCooperativeKernel((const void*)snn_kernel,
                                             dim3(GRID), dim3(NTHR),
                                             args, 0, stream);
  if (rc != hipSuccess) {
    // Hand-rolled grid barrier; ~141 KB LDS -> 1 block/CU, grid == #CUs:
    // co-residency holds by construction under a plain launch.
    hipLaunchKernelGGL(snn_kernel, dim3(GRID), dim3(NTHR), 0, stream,
                       img, W, out, ws);
  }
}

// Round 18
// 5336.067 us; speedup vs baseline: 1.4793x; 1.4793x over previous
//
#include <hip/hip_runtime.h>

// SNN-MNIST forward + STDP, MI355X persistent cooperative kernel.
// Round 22: barrier-release fix driven by r21's measurement (pure release
// ~3.75 us/barrier, ~7.5 us/step for the pair = half the unexplained
// budget). Hypothesis: 256 packed flags = 16 sc1 stores per 64B line
// serialize at the MALL bank under concurrent poll traffic. Fix: spread
// flags to one per 32B (2/line, 8x less serialization); poll = 4
// independent 4B sc1 loads per lane (one round trip, 64 lanes x 4 = 256).
// Everything else byte-identical to r20 (6310 us, absmax 2.0).
// Decision: <=5900 confirmed; ~6300 null -> single-aggregator next.

#define T_STEPS 200
#define BATCH   256
#define INQ     784
#define NOUT    400
#define NP      512
#define GRID    256
#define NTHR    512
#define NBN     7              // n-blocks of 64 cols
#define ABLK    175            // 25 i-blocks x 7 n-blocks

// ws layout (float offsets)
#define OFF_WT    0            // Wt [785][512] (row 784 = zero pad for gather)
#define OFF_SYN   401920       // syn [256][512]         (block-private)
#define OFF_MEM   532992       // mem [256][512]         (block-private)
#define OFF_SPPO  664064       // interleaved (spk,post): [256][1024]  (sc1)
#define OFF_TRM   926208       // merged (tr,img): [256][1568]        (sc1)
#define OFF_WIN   1327616      // int win[256]           (block-private)
#define OFF_ANY   1327872      // u32 anyspk[2][256]     (sc1, ping-pong)
#define OFF_BARF  1328384      // u32 barf[256*8]: flags spread 32B apart
#define WS_FLOATS 1332224

// ---- agent-coherent (sc1) access helpers ----
__device__ __forceinline__ float ld_coh(const float* p) {
  return __hip_atomic_load(p, __ATOMIC_RELAXED, __HIP_MEMORY_SCOPE_AGENT);
}
__device__ __forceinline__ float2 ld_coh2(const float* p) {
  union { unsigned long long u; float2 f; } c;
  c.u = __hip_atomic_load((const unsigned long long*)p, __ATOMIC_RELAXED,
                          __HIP_MEMORY_SCOPE_AGENT);
  return c.f;
}
__device__ __forceinline__ void st_coh(float* p, float v) {
  __hip_atomic_store(p, v, __ATOMIC_RELAXED, __HIP_MEMORY_SCOPE_AGENT);
}
__device__ __forceinline__ void st_coh2(float* p, float2 v) {
  union { unsigned long long u; float2 f; } c; c.f = v;
  __hip_atomic_store((unsigned long long*)p, c.u, __ATOMIC_RELAXED,
                     __HIP_MEMORY_SCOPE_AGENT);
}
__device__ __forceinline__ void st_cohu(unsigned* p, unsigned v) {
  __hip_atomic_store(p, v, __ATOMIC_RELAXED, __HIP_MEMORY_SCOPE_AGENT);
}
__device__ __forceinline__ unsigned ld_cohu(const unsigned* p) {
  return __hip_atomic_load(p, __ATOMIC_RELAXED, __HIP_MEMORY_SCOPE_AGENT);
}
__device__ __forceinline__ unsigned long long ld_cohu64(const unsigned long long* p) {
  return __hip_atomic_load(p, __ATOMIC_RELAXED, __HIP_MEMORY_SCOPE_AGENT);
}

__device__ __forceinline__ void gl_lds16c(const float* g, float* l) {      // sc1
  __builtin_amdgcn_global_load_lds(
      (const __attribute__((address_space(1))) void*)g,
      (__attribute__((address_space(3))) void*)l, 16, 0, 0x10);
}

// All-to-all flag barrier, k = 1-based ordinal. Flags spread one per 32B
// (2 per 64B line): parallel store landing, no per-line serialization.
// Poll: lane l checks flags 4l..4l+3 (4 independent 4B sc1 loads = one
// round trip); __all over 64 lanes covers all 256 blocks.
__device__ __forceinline__ void gbar(unsigned* barf, unsigned k, int blk) {
  __syncthreads();
  if (threadIdx.x == 0)
    st_cohu(barf + blk * 8, k);
  if (threadIdx.x < 64) {
    const unsigned* p = barf + (threadIdx.x << 5);   // flag 4l at (4l)*8
    for (;;) {
      unsigned f0 = ld_cohu(p);
      unsigned f1 = ld_cohu(p + 8);
      unsigned f2 = ld_cohu(p + 16);
      unsigned f3 = ld_cohu(p + 24);
      unsigned mn = min(min(f0, f1), min(f2, f3));
      if (__all(mn >= k)) break;
      __builtin_amdgcn_s_sleep(1);
    }
  }
  __syncthreads();
}

__global__ void __launch_bounds__(NTHR, 2) snn_kernel(
    const float* __restrict__ img,   // [200][256][784]
    const float* __restrict__ Win,   // [400][784]
    float* __restrict__ out,         // mem_rec | spk_rec | W_final
    float* ws)
{
  float* Wt    = ws + OFF_WT;
  float* syn   = ws + OFF_SYN;
  float* mem   = ws + OFF_MEM;
  float* sppo  = ws + OFF_SPPO;
  float* trm   = ws + OFF_TRM;
  int*   win   = (int*)(ws + OFF_WIN);
  unsigned* anyspk = (unsigned*)(ws + OFF_ANY);
  unsigned* barf   = (unsigned*)(ws + OFF_BARF);

  float* mem_rec = out;
  float* spk_rec = out + (size_t)T_STEPS * BATCH * NOUT;
  float* Wout    = out + (size_t)2 * T_STEPS * BATCH * NOUT;

  const int tid = threadIdx.x;
  const int blk = blockIdx.x;
  unsigned bt = 0;                    // barrier ordinal

  __shared__ float stg_ti[16384];     // merged (tr,img) [256][64], persistent
  __shared__ float stg_sp[2][8192];   // sppo chunk dbuf [64][128]
  __shared__ float s_trrow[INQ];      // block-own pre-trace row
  __shared__ int s_list[2][832];      // double-buffered active lists
  __shared__ int s_cnt2[2];
  __shared__ int s_any;
  __shared__ int s_red[8];

  // phase-2 geometry: 25 i-blocks (32 rows) x 7 n-blocks (64 cols)
  const int bi = blk / NBN, bn = blk % NBN;
  const int ib0 = bi * 32, nb0 = bn * 64;
  const int scol = 2 * nb0 + (tid & 31) * 4;        // sppo col
  int colf = 2 * ib0 + (tid & 15) * 4;
  if (colf > 2 * INQ - 4) colf = 2 * INQ - 4;

  // per-thread phase-2 tile: 2 i-rows x 2 n-cols
  const int ib = ib0 + (tid >> 5) * 2;
  const int nb = nb0 + (tid & 31) * 2;
  const int tioff = (tid >> 5) * 4;
  const int soff  = (tid & 31) * 4;

  // ---- init: Wt[i][n] = Win[n][i]; merged row {tr=0, img_0} ----
  for (int e = blk * NTHR + tid; e < NOUT * INQ; e += GRID * NTHR) {
    int n = e / INQ, i = e % INQ;
    st_coh(Wt + (size_t)i * NP + n, Win[e]);
  }
  for (int i = tid; i < INQ; i += NTHR)
    st_coh2(trm + (size_t)blk * (2 * INQ) + 2 * i,
            make_float2(0.0f, img[(size_t)blk * INQ + i]));
  for (int i = tid; i < INQ; i += NTHR) s_trrow[i] = 0.0f;
  // init compaction of img[0] into s_list[0] (wave 0)
  if (tid < 64) {
    const float* im0 = img + (size_t)blk * INQ;
    int base = 0;
    for (int c = 0; c < INQ; c += 64) {
      int i = c + tid;
      bool act = (i < INQ) && (im0[i] != 0.0f);
      unsigned long long m = __ballot(act);
      if (act)
        s_list[0][base + (int)__popcll(m & ((1ull << tid) - 1ull))] = i;
      base += (int)__popcll(m);
    }
    if (tid == 0) {
      int cr = (base + 63) & ~63;
      for (int j = base; j < cr; ++j) s_list[0][j] = 784;
      s_cnt2[0] = cr;
    }
  }
  ++bt; gbar(barf, bt, blk);

  // step-0 ti prefetch (8 passes x 32 rows; lane-contiguous LDS dest)
  if (blk < ABLK) {
    #pragma unroll
    for (int q = 0; q < 8; ++q) {
      int br = q * 32 + (tid >> 4);
      gl_lds16c(trm + (size_t)br * (2 * INQ) + colf,
                &stg_ti[br * 64 + (tid & 15) * 4]);
    }
  }

  for (int t = 0; t < T_STEPS; ++t) {
    const int tn = (t + 1 < T_STEPS) ? t + 1 : t;

    // ================= phase 1: block b = batch row =================
    {
      const int b = blk;
      const float* imrow = img + ((size_t)t * BATCH + b) * INQ;
      const float* imnext = img + ((size_t)tn * BATCH + b) * INQ;
      float* trmrow = trm + (size_t)b * (2 * INQ);
      if (tid < 448) {
        // tids 0-447: trace recurrence from block-own LDS row; write merged
        // {tr_{t+1}, img_{t+1}} pair for next step's phase 2
        for (int i = tid; i < INQ; i += 448) {
          float trv = fmaf(0.9f, s_trrow[i], imrow[i]);
          s_trrow[i] = trv;
          st_coh2(trmrow + 2 * i, make_float2(trv, imnext[i]));
        }
      } else {
        // wave 7: anyspk gather + compaction of img[t+1] into buf[(t+1)&1]
        const int l = tid - 448;
        unsigned long long ax = 0ull, ay = 0ull;
        if (t > 0) {
          const unsigned long long* ap =
              (const unsigned long long*)(anyspk + ((t - 1) & 1) * 256) +
              (l << 1);
          ax = ld_cohu64(ap);
          ay = ld_cohu64(ap + 1);
        }
        int* lst = s_list[(t + 1) & 1];
        int base = 0;
        for (int c = 0; c < INQ; c += 64) {
          int i = c + l;
          bool act = (i < INQ) && (imnext[i] != 0.0f);
          unsigned long long m = __ballot(act);
          if (act) lst[base + (int)__popcll(m & ((1ull << l) - 1ull))] = i;
          base += (int)__popcll(m);
        }
        int anyv = __any((ax | ay) != 0ull);
        if (l == 0) {
          int cr = (base + 63) & ~63;
          for (int j = base; j < cr; ++j) lst[j] = 784;  // zero pad row
          s_cnt2[(t + 1) & 1] = cr;
          s_any = anyv;
        }
      }
      __syncthreads();
      const int cnt = s_cnt2[t & 1];    // multiple of 64 (precomputed)
      const int* lst = s_list[t & 1];
      const int anyPrev = (t > 0) ? s_any : 0;
      const int wPrev = win[b];
      int localmin = 0x7fffffff;

      if (tid < NOUT) {
        const int n0 = tid;             // one neuron per thread
        const size_t sidx = (size_t)b * NP + n0;
        float* sprow = sppo + (size_t)b * 2 * NP + 2 * n0;
        float2 sp2 = ld_coh2(sprow);    // (spk, post)
        float sv = syn[sidx];
        if (anyPrev && n0 != wPrev) sv -= 0.1f;
        float c0 = 0.f;
        for (int j = 0; j < cnt; j += 64) {  // 64 coherent loads in flight
          float wv[64];
          #pragma unroll
          for (int u = 0; u < 64; ++u)
            wv[u] = ld_coh(Wt + (size_t)lst[j + u] * NP + n0);
          #pragma unroll
          for (int u = 0; u < 64; ++u) c0 += wv[u];
        }
        float mv = mem[sidx];
        float syn0 = fmaf(0.9f, sv, c0);
        float r0 = (mv > 1.0f) ? 1.0f : 0.0f;
        float m0 = fmaf(0.8f, mv, syn0) - r0;
        float s0 = (m0 > 1.0f) ? 1.0f : 0.0f;
        syn[sidx] = syn0;
        mem[sidx] = m0;
        float p0 = fmaf(0.9f, sp2.y, s0);
        st_coh2(sprow, make_float2(s0, p0));
        const size_t ridx = (size_t)t * BATCH * NOUT + (size_t)b * NOUT + n0;
        mem_rec[ridx] = m0;
        spk_rec[ridx] = s0;
        if (s0 != 0.f) localmin = n0;
      }
      // ballot winner reduction
      unsigned long long mm = __ballot(localmin != 0x7fffffff);
      int wmin = 0x7fffffff;
      if (mm) {
        int src = __ffsll(mm) - 1;
        wmin = __shfl(localmin, src);
      }
      if ((tid & 63) == 0) s_red[tid >> 6] = wmin;
      __syncthreads();
      if (tid == 0) {
        int w4 = min(min(min(s_red[0], s_red[1]), min(s_red[2], s_red[3])),
                     min(min(s_red[4], s_red[5]), min(s_red[6], s_red[7])));
        win[b] = (w4 == 0x7fffffff) ? 0 : w4;
        st_cohu(anyspk + (t & 1) * 256 + blk,
                (w4 != 0x7fffffff) ? 1u : 0u);
      }
    }
    ++bt; gbar(barf, bt, blk);

    // ================= phase 2: STDP weight update =================
    // ti resident in LDS; 4 merged chunks of 64 b-rows, 2-deep sppo dbuf.
    if (blk < ABLK) {
      const bool active = (ib < INQ) && (nb < NOUT);

      float2 wl0, wl1;
      if (active) {
        wl0 = ld_coh2(Wt + (size_t)(ib + 0) * NP + nb);
        wl1 = ld_coh2(Wt + (size_t)(ib + 1) * NP + nb);
      }

      float a00 = 0, a01 = 0, a10 = 0, a11 = 0;

      #define SPSTG(c_, buf_) {                                                \
        for (int q = 0; q < 4; ++q) {                                          \
          int br = (c_) * 64 + q * 16 + (tid >> 5);                            \
          gl_lds16c(sppo + (size_t)br * 1024 + scol,                           \
                    &stg_sp[buf_][(q * 16 + (tid >> 5)) * 128 +                \
                                  (tid & 31) * 4]);                            \
        }                                                                      \
      }

      SPSTG(0, 0); SPSTG(1, 1);
      for (int c = 0; c < 4; ++c) {
        if (c == 0) __builtin_amdgcn_s_waitcnt(0x0F74);  // vmcnt(4)
        else        __builtin_amdgcn_s_waitcnt(0x0F70);  // vmcnt(0)
        __builtin_amdgcn_sched_barrier(0);
        __builtin_amdgcn_s_barrier();
        if (c >= 1 && c <= 2) SPSTG(c + 1, (c + 1) & 1);
        if (active) {
          const float* Lti = &stg_ti[(c * 64) * 64 + tioff];
          const float* Lsp = &stg_sp[c & 1][soff];
          #pragma unroll 8
          for (int bb = 0; bb < 64; ++bb) {       // b ascending: exact order
            float4 q4 = *(const float4*)(Lti + bb * 64);   // tr0,im0,tr1,im1
            float4 sp = *(const float4*)(Lsp + bb * 128);  // s0,p0,s1,p1
            a00 = fmaf(q4.x, sp.x, fmaf(q4.y, -sp.y, a00));
            a01 = fmaf(q4.x, sp.z, fmaf(q4.y, -sp.w, a01));
            a10 = fmaf(q4.z, sp.x, fmaf(q4.w, -sp.y, a10));
            a11 = fmaf(q4.z, sp.z, fmaf(q4.w, -sp.w, a11));
          }
        }
      }
      #undef SPSTG

      // RACE FIX: all waves finish chunk-3 LDS reads before the prefetch
      // overwrites stg_ti.
      __builtin_amdgcn_s_barrier();

      // next-step ti prefetch streams in the epilogue + barrier shadow
      if (t + 1 < T_STEPS) {
        #pragma unroll
        for (int q = 0; q < 8; ++q) {
          int br = q * 32 + (tid >> 4);
          gl_lds16c(trm + (size_t)br * (2 * INQ) + colf,
                    &stg_ti[br * 64 + (tid & 15) * 4]);
        }
      }
      if (active) {
        float2 wv;
        wv = wl0;
        wv.x = fminf(fmaxf(wv.x + 1e-3f * a00, 0.f), 1.f);
        wv.y = fminf(fmaxf(wv.y + 1e-3f * a01, 0.f), 1.f);
        st_coh2(Wt + (size_t)(ib + 0) * NP + nb, wv);
        wv = wl1;
        wv.x = fminf(fmaxf(wv.x + 1e-3f * a10, 0.f), 1.f);
        wv.y = fminf(fmaxf(wv.y + 1e-3f * a11, 0.f), 1.f);
        st_coh2(Wt + (size_t)(ib + 1) * NP + nb, wv);
      }
    }
    ++bt; gbar(barf, bt, blk);
  }

  // ---- final: W_out[n][i] = Wt[i][n] ----
  for (int e = blk * NTHR + tid; e < NOUT * INQ; e += GRID * NTHR) {
    int n = e / INQ, i = e % INQ;
    Wout[e] = ld_coh(Wt + (size_t)i * NP + n);
  }
}

extern "C" void kernel_launch(void* const* d_in, const int* in_sizes, int n_in,
                              void* d_out, int out_size, void* d_ws, size_t ws_size,
                              hipStream_t stream) {
  const float* img = (const float*)d_in[0];
  const float* W   = (const float*)d_in[1];
  float* out = (float*)d_out;
  float* ws  = (float*)d_ws;

  hipMemsetAsync(d_ws, 0, (size_t)WS_FLOATS * sizeof(float), stream);

  void* args[] = { (void*)&img, (void*)&W, (void*)&out, (void*)&ws };
  hipError_t rc = hipLaunchCooperativeKernel((const void*)snn_kernel,
                                             dim3(GRID), dim3(NTHR),
                                             args, 0, stream);
  if (rc != hipSuccess) {
    // Hand-rolled grid barrier; ~141 KB LDS -> 1 block/CU, grid == #CUs:
    // co-residency holds by construction under a plain launch.
    hipLaunchKernelGGL(snn_kernel, dim3(GRID), dim3(NTHR), 0, stream,
                       img, W, out, ws);
  }
}